// Round 13
// baseline (765.730 us; speedup 1.0000x reference)
//
#include <hip/hip_runtime.h>
#include <hip/hip_bf16.h>
#include <cstdint>
#include <cstddef>

typedef __hip_bfloat16 BF16;
typedef __bf16 bf16x8 __attribute__((ext_vector_type(8)));
typedef float floatx4 __attribute__((ext_vector_type(4)));
typedef float f32x16 __attribute__((ext_vector_type(16)));

// ---------------- workspace layout (bytes) ----------------
static constexpr size_t OFF_WQKV  = 0;
static constexpr size_t OFF_WPROJ = OFF_WQKV  + (size_t)1536 * 512 * 2;
static constexpr size_t OFF_W1    = OFF_WPROJ + (size_t)512 * 512 * 2;
static constexpr size_t OFF_W2    = OFF_W1    + (size_t)2048 * 512 * 2;
static constexpr size_t OFF_H     = OFF_W2    + (size_t)512 * 2048 * 2;
static constexpr size_t OFF_QKV   = OFF_H     + (size_t)65536 * 512 * 2;
static constexpr size_t OFF_ATTN  = OFF_QKV   + (size_t)65536 * 1536 * 2;
static constexpr size_t OFF_M     = OFF_QKV;   // MLP intermediate reuses qkv+attn region

// ---------------- merged weight prep: fp32 (K,N) -> bf16 (N,K), 4 weights ----
__global__ __launch_bounds__(256) void wprep_all(
    const float* __restrict__ qkvw, const float* __restrict__ projw,
    const float* __restrict__ w1, const float* __restrict__ w2,
    BF16* __restrict__ o_qkv, BF16* __restrict__ o_proj,
    BF16* __restrict__ o_w1, BF16* __restrict__ o_w2) {
  __shared__ float t[64][65];
  int b = blockIdx.x;
  const float* W; BF16* Wt; int K, N, bx, by;
  if (b < 192)      {          W = qkvw;  Wt = o_qkv;  K = 512;  N = 1536; bx = b % 24; by = b / 24; }
  else if (b < 256) { b -= 192; W = projw; Wt = o_proj; K = 512;  N = 512;  bx = b % 8;  by = b / 8; }
  else if (b < 512) { b -= 256; W = w1;    Wt = o_w1;   K = 512;  N = 2048; bx = b % 32; by = b / 32; }
  else              { b -= 512; W = w2;    Wt = o_w2;   K = 2048; N = 512;  bx = b % 8;  by = b / 8; }
  const int n0 = bx * 64, k0 = by * 64;
  const int tid = threadIdx.x;
#pragma unroll
  for (int it = 0; it < 16; ++it) {
    int idx = it * 256 + tid;
    int r = idx >> 6, c = idx & 63;
    t[r][c] = W[(size_t)(k0 + r) * N + (n0 + c)];
  }
  __syncthreads();
#pragma unroll
  for (int it = 0; it < 16; ++it) {
    int idx = it * 256 + tid;
    int r = idx >> 6, c = idx & 63;
    Wt[(size_t)(n0 + r) * K + (k0 + c)] = __float2bfloat16(t[c][r]);
  }
}

// ---------------- LayerNorm (fp32 in, bf16 out), one wave per row ----------------
__global__ __launch_bounds__(256) void ln_kernel(
    const float* __restrict__ x, const float* __restrict__ w,
    const float* __restrict__ b, BF16* __restrict__ out) {
  const int lane = threadIdx.x & 63;
  const size_t row = (size_t)blockIdx.x * 4 + (threadIdx.x >> 6);
  const float* xr = x + row * 512 + lane * 8;
  float xv[8], wv[8], bv[8];
  *(float4*)&xv[0] = *(const float4*)xr;
  *(float4*)&xv[4] = *(const float4*)(xr + 4);
  *(float4*)&wv[0] = *(const float4*)(w + lane * 8);
  *(float4*)&wv[4] = *(const float4*)(w + lane * 8 + 4);
  *(float4*)&bv[0] = *(const float4*)(b + lane * 8);
  *(float4*)&bv[4] = *(const float4*)(b + lane * 8 + 4);
  float s = 0.0f, ss = 0.0f;
#pragma unroll
  for (int t = 0; t < 8; ++t) { s += xv[t]; ss += xv[t] * xv[t]; }
#pragma unroll
  for (int o = 32; o > 0; o >>= 1) { s += __shfl_xor(s, o); ss += __shfl_xor(ss, o); }
  const float mu = s * (1.0f / 512.0f);
  const float var = ss * (1.0f / 512.0f) - mu * mu;
  const float rs = rsqrtf(var + 1e-5f);
  BF16 ob[8];
#pragma unroll
  for (int t = 0; t < 8; ++t)
    ob[t] = __float2bfloat16((xv[t] - mu) * rs * wv[t] + bv[t]);
  *(uint4*)(out + row * 512 + lane * 8) = *(const uint4*)ob;
}

// ---------------- helpers ----------------
__device__ __forceinline__ void gload16(const BF16* g, const char* l) {
  __builtin_amdgcn_global_load_lds(
      (const __attribute__((address_space(1))) void*)g,
      (__attribute__((address_space(3))) void*)l, 16, 0, 0);
}

__device__ __forceinline__ int win_src_row(int r) {
  const int b = r >> 12;
  const int s = (r >> 9) & 7;
  const int mm = (r >> 3) & 63;
  const int j = r & 7;
  const int p = (64 * mm + 8 * j + s + 4) & 4095;
  return (b << 12) + p;
}

// GELU via v*sigmoid(1.702v)  (max abs err ~0.02, well under tolerance here)
__device__ __forceinline__ float fast_gelu(float v) {
  const float t = __expf(v * -1.702f);
  return v * __builtin_amdgcn_rcpf(1.0f + t);
}

__device__ __forceinline__ uint2 pack4bf(float a, float b, float c, float d) {
  union { BF16 h[4]; uint2 u; } u;
  u.h[0] = __float2bfloat16(a); u.h[1] = __float2bfloat16(b);
  u.h[2] = __float2bfloat16(c); u.h[3] = __float2bfloat16(d);
  return u.u;
}

__device__ __forceinline__ f32x16 zero16() {
  f32x16 z;
#pragma unroll
  for (int i = 0; i < 16; ++i) z[i] = 0.0f;
  return z;
}

// ============ 256x256 GEMM, 32x32x16 MFMA (r9 schedule otherwise) ============
// 8 waves as 2(M)x4(N). Operand-swapped mfma_32x32x16(B, A, acc):
//   lane holds out-row = lane&31; reg-quad q gives 4 consecutive out-cols
//   q*8 + 4*(lane>>5) + [0..4)  -> float4-vectorizable epilogue.
// A-frag: row=lane&31, k=(lane>>5)*8+e; swizzled slot = (ks*2+hi)^(row&7).
// Staging/gates/barriers identical to round-9 verified config.
#define GATE4 asm volatile("s_waitcnt vmcnt(4)" ::: "memory")
#define GATE2 asm volatile("s_waitcnt vmcnt(2)" ::: "memory")
#define GATE0 asm volatile("s_waitcnt vmcnt(0)" ::: "memory")
#define BAR() __builtin_amdgcn_s_barrier()
#define WAITL() asm volatile("s_waitcnt lgkmcnt(0)" ::: "memory")

template <int ROWMAP, int EPI, int K>
__global__ __launch_bounds__(512, 2) void gemm256(
    const BF16* __restrict__ A, const BF16* __restrict__ Bt,
    const float* __restrict__ bias, const float* __restrict__ resid,
    float* __restrict__ outf, BF16* __restrict__ outb, int Nout) {
  __shared__ __align__(16) char smem[131072];
  const int tid = threadIdx.x, lane = tid & 63, wv = tid >> 6;
  const int wm = wv >> 2, wn = wv & 3;

  // T1: chunked XCD swizzle (nwg % 8 == 0 for all our grids)
  const int gx = gridDim.x;
  const int nwg = gx * gridDim.y;
  const int hwid = blockIdx.y * gx + blockIdx.x;
  const int swz = (hwid & 7) * (nwg >> 3) + (hwid >> 3);
  const int bm = swz / gx, bn = swz - bm * gx;
  const int row0 = bm * 256, col0 = bn * 256;

  // staging addressing: lane covers (row = c*64 + wv*8 + srow, 16B slot = lane&7)
  // pre-swizzled global source: k-slot = (lane&7) ^ srow
  const int srow = lane >> 3;
  const int scol = ((lane & 7) ^ srow) * 8;
  const BF16* Pa[2][2];
  const BF16* Pb[2][2];
#pragma unroll
  for (int mh = 0; mh < 2; ++mh)
#pragma unroll
    for (int c = 0; c < 2; ++c) {
      int ra = row0 + mh * 128 + c * 64 + wv * 8 + srow;
      if (ROWMAP == 1) ra = win_src_row(ra);
      Pa[mh][c] = A + (size_t)ra * K + scol;
      const int rb = col0 + mh * 128 + c * 64 + wv * 8 + srow;
      Pb[mh][c] = Bt + (size_t)rb * K + scol;
    }
  const int ldsw = wv * 1024;

  // fragment read offsets (swizzled, 32x32x16): row = lane&31, hi = lane>>5
  const int r31 = lane & 31;
  const int hi = lane >> 5;
  int sxk[4];
#pragma unroll
  for (int ks = 0; ks < 4; ++ks) sxk[ks] = ((ks * 2 + hi) ^ (r31 & 7)) * 16;
  const int raby = (wm * 64 + r31) * 128;  // + m*4096 + mh*16384
  const int rbby = (wn * 32 + r31) * 128;  // + nh*16384 (B base +32768)

  f32x16 acc[2][2][2];   // [mh][m][nh], each 32(rows)x32(cols) tile
#pragma unroll
  for (int mh = 0; mh < 2; ++mh)
#pragma unroll
    for (int m = 0; m < 2; ++m)
#pragma unroll
      for (int nh = 0; nh < 2; ++nh) acc[mh][m][nh] = zero16();

  bf16x8 fa[2][4], fb0[4], fb1[4];

#define STG_A(half, dd) do {                                              \
    gload16(Pa[half][0], smem + (dd)*65536 + (half)*16384 + ldsw);        \
    gload16(Pa[half][1], smem + (dd)*65536 + (half)*16384 + 8192 + ldsw); \
  } while (0)
#define STG_B(half, dd) do {                                                      \
    gload16(Pb[half][0], smem + (dd)*65536 + 32768 + (half)*16384 + ldsw);        \
    gload16(Pb[half][1], smem + (dd)*65536 + 32768 + (half)*16384 + 8192 + ldsw); \
  } while (0)
#define ADV() do {                                          \
    Pa[0][0] += 64; Pa[0][1] += 64; Pa[1][0] += 64; Pa[1][1] += 64; \
    Pb[0][0] += 64; Pb[0][1] += 64; Pb[1][0] += 64; Pb[1][1] += 64; \
  } while (0)

#define RD_FA(mh, dd)                                                          \
  _Pragma("unroll")                                                            \
  for (int m = 0; m < 2; ++m)                                                  \
    _Pragma("unroll")                                                          \
    for (int ks = 0; ks < 4; ++ks)                                             \
      fa[m][ks] = *(const bf16x8*)(smem + (dd)*65536 + (mh)*16384 + raby + m*4096 + sxk[ks]);
#define RD_FB(dst, nh, dd)                                                     \
  _Pragma("unroll")                                                            \
  for (int ks = 0; ks < 4; ++ks)                                               \
    dst[ks] = *(const bf16x8*)(smem + (dd)*65536 + 32768 + (nh)*16384 + rbby + sxk[ks]);
// operand-swapped: mfma(B, A, acc)
#define MF(mh, nh, fbx)                                                        \
  __builtin_amdgcn_s_setprio(1);                                               \
  _Pragma("unroll")                                                            \
  for (int ks = 0; ks < 4; ++ks)                                               \
    _Pragma("unroll")                                                          \
    for (int m = 0; m < 2; ++m)                                                \
      acc[mh][m][nh] = __builtin_amdgcn_mfma_f32_32x32x16_bf16(                \
          fbx[ks], fa[m][ks], acc[mh][m][nh], 0, 0, 0);                        \
  __builtin_amdgcn_s_setprio(0)

  // ---------------- prologue: stage K-tile 0 into d0 (order A0,B0,B1,A1) ----
  STG_A(0, 0);
  STG_B(0, 0);
  STG_B(1, 0);
  STG_A(1, 0);
  ADV();
  GATE4;   // A0,B0 landed; B1,A1 in flight
  BAR();

  constexpr int NT = K / 64;
  // ---------------- steady K-tiles 0..NT-2 (one trailing BAR per phase) ----
  for (int t = 0; t < NT - 1; ++t) {
    const int dd = t & 1, de = dd ^ 1;
    // phase 0: q(0,0); stage next A0
    RD_FA(0, dd); RD_FB(fb0, 0, dd);
    STG_A(0, de);
    WAITL();
    MF(0, 0, fb0);
    GATE4; BAR();
    // phase 1: q(0,1); stage next B0
    RD_FB(fb1, 1, dd);
    STG_B(0, de);
    WAITL();
    MF(0, 1, fb1);
    GATE4; BAR();
    // phase 2: q(1,1); stage next B1
    RD_FA(1, dd);
    STG_B(1, de);
    WAITL();
    MF(1, 1, fb1);
    BAR();
    // phase 3: q(1,0); stage next A1
    STG_A(1, de);
    MF(1, 0, fb0);
    GATE4; BAR();
    ADV();
  }
  // ---------------- tail K-tile NT-1 (no staging; drain 2 -> 0) ------------
  {
    const int dd = (NT - 1) & 1;
    RD_FA(0, dd); RD_FB(fb0, 0, dd);
    WAITL();
    MF(0, 0, fb0);
    GATE2; BAR();
    RD_FB(fb1, 1, dd);
    WAITL();
    MF(0, 1, fb1);
    GATE0; BAR();
    RD_FA(1, dd);
    WAITL();
    MF(1, 1, fb1);
    MF(1, 0, fb0);
  }
#undef STG_A
#undef STG_B
#undef ADV
#undef RD_FA
#undef RD_FB
#undef MF

  // ------- epilogue: lane owns out-row lane&31; reg-quad q -> 4 cols -------
  const int hi4 = hi * 4;
  float4 bsv[2][4];
#pragma unroll
  for (int nh = 0; nh < 2; ++nh)
#pragma unroll
    for (int q = 0; q < 4; ++q)
      bsv[nh][q] = *(const float4*)&bias[col0 + nh * 128 + wn * 32 + q * 8 + hi4];

#pragma unroll
  for (int mh = 0; mh < 2; ++mh)
#pragma unroll
    for (int m = 0; m < 2; ++m) {
      const int r = row0 + mh * 128 + wm * 64 + m * 32 + r31;
      size_t rowbase;
      if (EPI == 2) {
        const int b = r >> 12;
        const int np = (r >> 3) & 511;
        const int ap = r & 7;
        const int io = ((ap << 9) + np + 4) & 4095;
        rowbase = ((size_t)(b << 12) + io) * 512;
      } else {
        rowbase = (size_t)r * Nout;
      }
#pragma unroll
      for (int nh = 0; nh < 2; ++nh) {
        f32x16 a = acc[mh][m][nh];
#pragma unroll
        for (int q = 0; q < 4; ++q) {
          const int c0 = col0 + nh * 128 + wn * 32 + q * 8 + hi4;
          float v0 = a[q * 4 + 0] + bsv[nh][q].x;
          float v1 = a[q * 4 + 1] + bsv[nh][q].y;
          float v2 = a[q * 4 + 2] + bsv[nh][q].z;
          float v3 = a[q * 4 + 3] + bsv[nh][q].w;
          if (EPI == 0) {
            *(uint2*)&outb[rowbase + c0] = pack4bf(v0, v1, v2, v3);
          } else if (EPI == 1) {
            *(uint2*)&outb[rowbase + c0] = pack4bf(
                fast_gelu(v0), fast_gelu(v1), fast_gelu(v2), fast_gelu(v3));
          } else if (EPI == 2) {
            const float4 rv = *(const float4*)&resid[rowbase + c0];
            float4 ov = {rv.x + v0, rv.y + v1, rv.z + v2, rv.w + v3};
            *(float4*)&outf[rowbase + c0] = ov;
          } else {
            float4 ov = *(float4*)&outf[rowbase + c0];
            ov.x += v0; ov.y += v1; ov.z += v2; ov.w += v3;
            *(float4*)&outf[rowbase + c0] = ov;
          }
        }
      }
    }
}

// ---------------- per-window attention (round-9 proven version) ----------------
__global__ __launch_bounds__(64) void attn_kernel(
    const BF16* __restrict__ qkv, BF16* __restrict__ out) {
  const int w = blockIdx.x;
  const int lane = threadIdx.x;
  const int qi = lane >> 3, kj = lane & 7;
  __shared__ __align__(16) BF16 sm[8 * 1544];
  const BF16* src = qkv + (size_t)w * 8 * 1536;
#pragma unroll
  for (int rr = 0; rr < 8; ++rr) {
    const uint4* s4 = (const uint4*)(src + (size_t)rr * 1536);
    uint4* d4 = (uint4*)(&sm[rr * 1544]);
#pragma unroll
    for (int c = 0; c < 3; ++c) d4[c * 64 + lane] = s4[c * 64 + lane];
  }
  __syncthreads();

  const int s = (w >> 6) & 7, mm = w & 63;
  const int pi = 64 * mm + 8 * qi + s;
  const int pj = 64 * mm + 8 * kj + s;
  const int ri = pi >= 4092 ? 2 : (pi >= 4088 ? 1 : 0);
  const int rj = pj >= 4092 ? 2 : (pj >= 4088 ? 1 : 0);
  const float maskv = (ri != rj) ? -100.0f : 0.0f;

  for (int h = 0; h < 8; ++h) {
    const BF16* qp = &sm[qi * 1544 + h * 64];
    const BF16* kp = &sm[kj * 1544 + 512 + h * 64];
    float acc = 0.0f;
#pragma unroll
    for (int d0 = 0; d0 < 8; ++d0) {
      bf16x8 qv = *(const bf16x8*)(qp + d0 * 8);
      bf16x8 kv = *(const bf16x8*)(kp + d0 * 8);
#pragma unroll
      for (int t = 0; t < 8; ++t) acc += (float)qv[t] * (float)kv[t];
    }
    float sc = acc * 0.125f + maskv;
    float mx = sc;
    mx = fmaxf(mx, __shfl_xor(mx, 1, 8));
    mx = fmaxf(mx, __shfl_xor(mx, 2, 8));
    mx = fmaxf(mx, __shfl_xor(mx, 4, 8));
    float e = __expf(sc - mx);
    float den = e;
    den += __shfl_xor(den, 1, 8);
    den += __shfl_xor(den, 2, 8);
    den += __shfl_xor(den, 4, 8);
    const float P = e / den;

    float o8[8];
#pragma unroll
    for (int t = 0; t < 8; ++t) o8[t] = 0.0f;
#pragma unroll
    for (int j2 = 0; j2 < 8; ++j2) {
      float p2 = __shfl(P, j2, 8);
      bf16x8 vv = *(const bf16x8*)(&sm[j2 * 1544 + 1024 + h * 64 + kj * 8]);
#pragma unroll
      for (int t = 0; t < 8; ++t) o8[t] += p2 * (float)vv[t];
    }
    BF16 ob[8];
#pragma unroll
    for (int t = 0; t < 8; ++t) ob[t] = __float2bfloat16(o8[t]);
    *(uint4*)(&out[((size_t)w * 8 + qi) * 512 + h * 64 + kj * 8]) = *(const uint4*)ob;
  }
}

// ---------------- launch ----------------
extern "C" void kernel_launch(void* const* d_in, const int* in_sizes, int n_in,
                              void* d_out, int out_size, void* d_ws, size_t ws_size,
                              hipStream_t stream) {
  (void)in_sizes; (void)n_in; (void)out_size; (void)ws_size;
  const float* x     = (const float*)d_in[0];
  const float* n1w   = (const float*)d_in[1];
  const float* n1b   = (const float*)d_in[2];
  const float* qkvw  = (const float*)d_in[3];
  const float* qkvb  = (const float*)d_in[4];
  const float* projw = (const float*)d_in[5];
  const float* projb = (const float*)d_in[6];
  const float* n2w   = (const float*)d_in[7];
  const float* n2b   = (const float*)d_in[8];
  const float* w1    = (const float*)d_in[9];
  const float* b1    = (const float*)d_in[10];
  const float* w2    = (const float*)d_in[11];
  const float* b2    = (const float*)d_in[12];
  float* out = (float*)d_out;
  char* ws = (char*)d_ws;

  BF16* wt_qkv  = (BF16*)(ws + OFF_WQKV);
  BF16* wt_proj = (BF16*)(ws + OFF_WPROJ);
  BF16* wt_w1   = (BF16*)(ws + OFF_W1);
  BF16* wt_w2   = (BF16*)(ws + OFF_W2);
  BF16* hbuf    = (BF16*)(ws + OFF_H);
  BF16* qkvbuf  = (BF16*)(ws + OFF_QKV);
  BF16* attnbuf = (BF16*)(ws + OFF_ATTN);
  BF16* mbuf    = (BF16*)(ws + OFF_M);

  wprep_all<<<768, 256, 0, stream>>>(qkvw, projw, w1, w2,
                                     wt_qkv, wt_proj, wt_w1, wt_w2);

  ln_kernel<<<16384, 256, 0, stream>>>(x, n1w, n1b, hbuf);
  gemm256<1, 0, 512><<<dim3(6, 256), 512, 0, stream>>>(hbuf, wt_qkv, qkvb, nullptr, nullptr, qkvbuf, 1536);
  attn_kernel<<<8192, 64, 0, stream>>>(qkvbuf, attnbuf);
  gemm256<0, 2, 512><<<dim3(2, 256), 512, 0, stream>>>(attnbuf, wt_proj, projb, x, out, nullptr, 512);
  ln_kernel<<<16384, 256, 0, stream>>>(out, n2w, n2b, hbuf);
  gemm256<0, 1, 512><<<dim3(8, 256), 512, 0, stream>>>(hbuf, wt_w1, b1, nullptr, nullptr, mbuf, 2048);
  gemm256<0, 3, 2048><<<dim3(2, 256), 512, 0, stream>>>(mbuf, wt_w2, b2, nullptr, out, nullptr, 512);
}

// Round 14
// 687.186 us; speedup vs baseline: 1.1143x; 1.1143x over previous
//
#include <hip/hip_runtime.h>
#include <hip/hip_bf16.h>
#include <cstdint>
#include <cstddef>

typedef __hip_bfloat16 BF16;
typedef __bf16 bf16x8 __attribute__((ext_vector_type(8)));
typedef float floatx4 __attribute__((ext_vector_type(4)));

// ---------------- workspace layout (bytes) ----------------
static constexpr size_t OFF_WQKV  = 0;
static constexpr size_t OFF_WPROJ = OFF_WQKV  + (size_t)1536 * 512 * 2;
static constexpr size_t OFF_W1    = OFF_WPROJ + (size_t)512 * 512 * 2;
static constexpr size_t OFF_W2    = OFF_W1    + (size_t)2048 * 512 * 2;
static constexpr size_t OFF_H     = OFF_W2    + (size_t)512 * 2048 * 2;
static constexpr size_t OFF_QKV   = OFF_H     + (size_t)65536 * 512 * 2;
static constexpr size_t OFF_ATTN  = OFF_QKV   + (size_t)65536 * 1536 * 2;
static constexpr size_t OFF_M     = OFF_QKV;   // MLP intermediate reuses qkv+attn region

// ---------------- merged weight prep: fp32 (K,N) -> bf16 (N,K), 4 weights ----
__global__ __launch_bounds__(256) void wprep_all(
    const float* __restrict__ qkvw, const float* __restrict__ projw,
    const float* __restrict__ w1, const float* __restrict__ w2,
    BF16* __restrict__ o_qkv, BF16* __restrict__ o_proj,
    BF16* __restrict__ o_w1, BF16* __restrict__ o_w2) {
  __shared__ float t[64][65];
  int b = blockIdx.x;
  const float* W; BF16* Wt; int K, N, bx, by;
  if (b < 192)      {          W = qkvw;  Wt = o_qkv;  K = 512;  N = 1536; bx = b % 24; by = b / 24; }
  else if (b < 256) { b -= 192; W = projw; Wt = o_proj; K = 512;  N = 512;  bx = b % 8;  by = b / 8; }
  else if (b < 512) { b -= 256; W = w1;    Wt = o_w1;   K = 512;  N = 2048; bx = b % 32; by = b / 32; }
  else              { b -= 512; W = w2;    Wt = o_w2;   K = 2048; N = 512;  bx = b % 8;  by = b / 8; }
  const int n0 = bx * 64, k0 = by * 64;
  const int tid = threadIdx.x;
#pragma unroll
  for (int it = 0; it < 16; ++it) {
    int idx = it * 256 + tid;
    int r = idx >> 6, c = idx & 63;
    t[r][c] = W[(size_t)(k0 + r) * N + (n0 + c)];
  }
  __syncthreads();
#pragma unroll
  for (int it = 0; it < 16; ++it) {
    int idx = it * 256 + tid;
    int r = idx >> 6, c = idx & 63;
    Wt[(size_t)(n0 + r) * K + (k0 + c)] = __float2bfloat16(t[c][r]);
  }
}

// ---------------- LayerNorm (fp32 in, bf16 out), one wave per row ----------------
__global__ __launch_bounds__(256) void ln_kernel(
    const float* __restrict__ x, const float* __restrict__ w,
    const float* __restrict__ b, BF16* __restrict__ out) {
  const int lane = threadIdx.x & 63;
  const size_t row = (size_t)blockIdx.x * 4 + (threadIdx.x >> 6);
  const float* xr = x + row * 512 + lane * 8;
  float xv[8], wv[8], bv[8];
  *(float4*)&xv[0] = *(const float4*)xr;
  *(float4*)&xv[4] = *(const float4*)(xr + 4);
  *(float4*)&wv[0] = *(const float4*)(w + lane * 8);
  *(float4*)&wv[4] = *(const float4*)(w + lane * 8 + 4);
  *(float4*)&bv[0] = *(const float4*)(b + lane * 8);
  *(float4*)&bv[4] = *(const float4*)(b + lane * 8 + 4);
  float s = 0.0f, ss = 0.0f;
#pragma unroll
  for (int t = 0; t < 8; ++t) { s += xv[t]; ss += xv[t] * xv[t]; }
#pragma unroll
  for (int o = 32; o > 0; o >>= 1) { s += __shfl_xor(s, o); ss += __shfl_xor(ss, o); }
  const float mu = s * (1.0f / 512.0f);
  const float var = ss * (1.0f / 512.0f) - mu * mu;
  const float rs = rsqrtf(var + 1e-5f);
  BF16 ob[8];
#pragma unroll
  for (int t = 0; t < 8; ++t)
    ob[t] = __float2bfloat16((xv[t] - mu) * rs * wv[t] + bv[t]);
  *(uint4*)(out + row * 512 + lane * 8) = *(const uint4*)ob;
}

// ---------------- helpers ----------------
__device__ __forceinline__ void gload16(const BF16* g, const char* l) {
  __builtin_amdgcn_global_load_lds(
      (const __attribute__((address_space(1))) void*)g,
      (__attribute__((address_space(3))) void*)l, 16, 0, 0);
}

__device__ __forceinline__ int win_src_row(int r) {
  const int b = r >> 12;
  const int s = (r >> 9) & 7;
  const int mm = (r >> 3) & 63;
  const int j = r & 7;
  const int p = (64 * mm + 8 * j + s + 4) & 4095;
  return (b << 12) + p;
}

// GELU via v*sigmoid(1.702v)  (max abs err ~0.02, well under tolerance here)
__device__ __forceinline__ float fast_gelu(float v) {
  const float t = __expf(v * -1.702f);
  return v * __builtin_amdgcn_rcpf(1.0f + t);
}

__device__ __forceinline__ uint2 pack4bf(float a, float b, float c, float d) {
  union { BF16 h[4]; uint2 u; } u;
  u.h[0] = __float2bfloat16(a); u.h[1] = __float2bfloat16(b);
  u.h[2] = __float2bfloat16(c); u.h[3] = __float2bfloat16(d);
  return u.u;
}

// ================= 256x256 8-phase GEMM (round-9 best config) =================
// 8 waves as 2(M)x4(N). Operand-swapped MFMA: lane holds (row=lane&15,
// cols=4*(lane>>4)+e) -> vectorized epilogue. One trailing barrier per phase.
#define GATE4 asm volatile("s_waitcnt vmcnt(4)" ::: "memory")
#define GATE2 asm volatile("s_waitcnt vmcnt(2)" ::: "memory")
#define GATE0 asm volatile("s_waitcnt vmcnt(0)" ::: "memory")
#define BAR() __builtin_amdgcn_s_barrier()
#define WAITL() asm volatile("s_waitcnt lgkmcnt(0)" ::: "memory")

template <int ROWMAP, int EPI, int K>
__global__ __launch_bounds__(512, 2) void gemm256(
    const BF16* __restrict__ A, const BF16* __restrict__ Bt,
    const float* __restrict__ bias, const float* __restrict__ resid,
    float* __restrict__ outf, BF16* __restrict__ outb, int Nout) {
  __shared__ __align__(16) char smem[131072];
  const int tid = threadIdx.x, lane = tid & 63, wv = tid >> 6;
  const int wm = wv >> 2, wn = wv & 3;

  // T1: chunked XCD swizzle (nwg % 8 == 0 for all our grids)
  const int gx = gridDim.x;
  const int nwg = gx * gridDim.y;
  const int hwid = blockIdx.y * gx + blockIdx.x;
  const int swz = (hwid & 7) * (nwg >> 3) + (hwid >> 3);
  const int bm = swz / gx, bn = swz - bm * gx;
  const int row0 = bm * 256, col0 = bn * 256;

  // staging addressing: lane covers (row = c*64 + wv*8 + srow, 16B slot = lane&7)
  // pre-swizzled global source: k-slot = (lane&7) ^ srow
  const int srow = lane >> 3;
  const int scol = ((lane & 7) ^ srow) * 8;
  const BF16* Pa[2][2];
  const BF16* Pb[2][2];
#pragma unroll
  for (int mh = 0; mh < 2; ++mh)
#pragma unroll
    for (int c = 0; c < 2; ++c) {
      int ra = row0 + mh * 128 + c * 64 + wv * 8 + srow;
      if (ROWMAP == 1) ra = win_src_row(ra);
      Pa[mh][c] = A + (size_t)ra * K + scol;
      const int rb = col0 + mh * 128 + c * 64 + wv * 8 + srow;
      Pb[mh][c] = Bt + (size_t)rb * K + scol;
    }
  const int ldsw = wv * 1024;

  // fragment read offsets (swizzled): slot s = ks*4 + (lane>>4), phys = s^(r16&7)
  const int r16 = lane & 15;
  const int sx0 = (((lane >> 4) + 0) ^ (r16 & 7)) * 16;
  const int sx1 = (((lane >> 4) + 4) ^ (r16 & 7)) * 16;
  const int raby = (wm * 64 + r16) * 128;  // + m2*2048 + mh*16384
  const int rbby = (wn * 32 + r16) * 128;  // + n2*2048 + nh*16384

  floatx4 acc[2][4][2][2];
#pragma unroll
  for (int mh = 0; mh < 2; ++mh)
#pragma unroll
    for (int m2 = 0; m2 < 4; ++m2)
#pragma unroll
      for (int nh = 0; nh < 2; ++nh)
#pragma unroll
        for (int n2 = 0; n2 < 2; ++n2)
          acc[mh][m2][nh][n2] = floatx4{0.f, 0.f, 0.f, 0.f};

  bf16x8 fa[4][2], fb0[2][2], fb1[2][2];

#define STG_A(half, dd) do {                                              \
    gload16(Pa[half][0], smem + (dd)*65536 + (half)*16384 + ldsw);        \
    gload16(Pa[half][1], smem + (dd)*65536 + (half)*16384 + 8192 + ldsw); \
  } while (0)
#define STG_B(half, dd) do {                                                      \
    gload16(Pb[half][0], smem + (dd)*65536 + 32768 + (half)*16384 + ldsw);        \
    gload16(Pb[half][1], smem + (dd)*65536 + 32768 + (half)*16384 + 8192 + ldsw); \
  } while (0)
#define ADV() do {                                          \
    Pa[0][0] += 64; Pa[0][1] += 64; Pa[1][0] += 64; Pa[1][1] += 64; \
    Pb[0][0] += 64; Pb[0][1] += 64; Pb[1][0] += 64; Pb[1][1] += 64; \
  } while (0)

#define RD_FA(mh, dd)                                                          \
  _Pragma("unroll")                                                            \
  for (int m2 = 0; m2 < 4; ++m2) {                                             \
    fa[m2][0] = *(const bf16x8*)(smem + (dd)*65536 + (mh)*16384 + raby + m2*2048 + sx0); \
    fa[m2][1] = *(const bf16x8*)(smem + (dd)*65536 + (mh)*16384 + raby + m2*2048 + sx1); \
  }
#define RD_FB(dst, nh, dd)                                                     \
  _Pragma("unroll")                                                            \
  for (int n2 = 0; n2 < 2; ++n2) {                                             \
    dst[n2][0] = *(const bf16x8*)(smem + (dd)*65536 + 32768 + (nh)*16384 + rbby + n2*2048 + sx0); \
    dst[n2][1] = *(const bf16x8*)(smem + (dd)*65536 + 32768 + (nh)*16384 + rbby + n2*2048 + sx1); \
  }
// operand-swapped: mfma(B, A, acc)
#define MF(mh, nh, fbx)                                                        \
  __builtin_amdgcn_s_setprio(1);                                               \
  _Pragma("unroll")                                                            \
  for (int ks = 0; ks < 2; ++ks)                                               \
    _Pragma("unroll")                                                          \
    for (int m2 = 0; m2 < 4; ++m2)                                             \
      _Pragma("unroll")                                                        \
      for (int n2 = 0; n2 < 2; ++n2)                                           \
        acc[mh][m2][nh][n2] = __builtin_amdgcn_mfma_f32_16x16x32_bf16(         \
            fbx[n2][ks], fa[m2][ks], acc[mh][m2][nh][n2], 0, 0, 0);            \
  __builtin_amdgcn_s_setprio(0)

  // ---------------- prologue: stage K-tile 0 into d0 (order A0,B0,B1,A1) ----
  STG_A(0, 0);
  STG_B(0, 0);
  STG_B(1, 0);
  STG_A(1, 0);
  ADV();
  GATE4;   // A0,B0 landed; B1,A1 in flight
  BAR();

  constexpr int NT = K / 64;
  // ---------------- steady K-tiles 0..NT-2 (one trailing BAR per phase) ----
  for (int t = 0; t < NT - 1; ++t) {
    const int dd = t & 1, de = dd ^ 1;
    // phase 0: q(0,0); stage next A0
    RD_FA(0, dd); RD_FB(fb0, 0, dd);
    STG_A(0, de);
    WAITL();
    MF(0, 0, fb0);
    GATE4; BAR();
    // phase 1: q(0,1); stage next B0
    RD_FB(fb1, 1, dd);
    STG_B(0, de);
    WAITL();
    MF(0, 1, fb1);
    GATE4; BAR();
    // phase 2: q(1,1); stage next B1
    RD_FA(1, dd);
    STG_B(1, de);
    WAITL();
    MF(1, 1, fb1);
    BAR();
    // phase 3: q(1,0); stage next A1
    STG_A(1, de);
    MF(1, 0, fb0);
    GATE4; BAR();
    ADV();
  }
  // ---------------- tail K-tile NT-1 (no staging; drain 2 -> 0) ------------
  {
    const int dd = (NT - 1) & 1;
    RD_FA(0, dd); RD_FB(fb0, 0, dd);
    WAITL();
    MF(0, 0, fb0);
    GATE2; BAR();
    RD_FB(fb1, 1, dd);
    WAITL();
    MF(0, 1, fb1);
    GATE0; BAR();
    RD_FA(1, dd);
    WAITL();
    MF(1, 1, fb1);
    MF(1, 0, fb0);
  }
#undef STG_A
#undef STG_B
#undef ADV
#undef RD_FA
#undef RD_FB
#undef MF

  // ---------------- epilogue (vectorized: lane owns 4 consecutive cols) ----
  const int g4 = (lane >> 4) * 4;
  float4 bsv[2][2];
#pragma unroll
  for (int nh = 0; nh < 2; ++nh)
#pragma unroll
    for (int n2 = 0; n2 < 2; ++n2)
      bsv[nh][n2] = *(const float4*)&bias[col0 + nh * 128 + wn * 32 + n2 * 16 + g4];

#pragma unroll
  for (int mh = 0; mh < 2; ++mh)
#pragma unroll
    for (int m2 = 0; m2 < 4; ++m2) {
      const int r = row0 + mh * 128 + wm * 64 + m2 * 16 + r16;
      size_t rowbase;
      if (EPI == 2) {
        const int b = r >> 12;
        const int np = (r >> 3) & 511;
        const int ap = r & 7;
        const int io = ((ap << 9) + np + 4) & 4095;
        rowbase = ((size_t)(b << 12) + io) * 512;
      } else {
        rowbase = (size_t)r * Nout;
      }
#pragma unroll
      for (int nh = 0; nh < 2; ++nh)
#pragma unroll
        for (int n2 = 0; n2 < 2; ++n2) {
          const int c0 = col0 + nh * 128 + wn * 32 + n2 * 16 + g4;
          floatx4 v = acc[mh][m2][nh][n2];
          v[0] += bsv[nh][n2].x; v[1] += bsv[nh][n2].y;
          v[2] += bsv[nh][n2].z; v[3] += bsv[nh][n2].w;
          if (EPI == 0) {
            *(uint2*)&outb[rowbase + c0] = pack4bf(v[0], v[1], v[2], v[3]);
          } else if (EPI == 1) {
            *(uint2*)&outb[rowbase + c0] = pack4bf(
                fast_gelu(v[0]), fast_gelu(v[1]), fast_gelu(v[2]), fast_gelu(v[3]));
          } else if (EPI == 2) {
            const float4 rv = *(const float4*)&resid[rowbase + c0];
            float4 ov = {rv.x + v[0], rv.y + v[1], rv.z + v[2], rv.w + v[3]};
            *(float4*)&outf[rowbase + c0] = ov;
          } else {
            float4 ov = *(float4*)&outf[rowbase + c0];
            ov.x += v[0]; ov.y += v[1]; ov.z += v[2]; ov.w += v[3];
            *(float4*)&outf[rowbase + c0] = ov;
          }
        }
    }
}

// ---------------- per-window attention (round-9 proven version) ----------------
__global__ __launch_bounds__(64) void attn_kernel(
    const BF16* __restrict__ qkv, BF16* __restrict__ out) {
  const int w = blockIdx.x;
  const int lane = threadIdx.x;
  const int qi = lane >> 3, kj = lane & 7;
  __shared__ __align__(16) BF16 sm[8 * 1544];
  const BF16* src = qkv + (size_t)w * 8 * 1536;
#pragma unroll
  for (int rr = 0; rr < 8; ++rr) {
    const uint4* s4 = (const uint4*)(src + (size_t)rr * 1536);
    uint4* d4 = (uint4*)(&sm[rr * 1544]);
#pragma unroll
    for (int c = 0; c < 3; ++c) d4[c * 64 + lane] = s4[c * 64 + lane];
  }
  __syncthreads();

  const int s = (w >> 6) & 7, mm = w & 63;
  const int pi = 64 * mm + 8 * qi + s;
  const int pj = 64 * mm + 8 * kj + s;
  const int ri = pi >= 4092 ? 2 : (pi >= 4088 ? 1 : 0);
  const int rj = pj >= 4092 ? 2 : (pj >= 4088 ? 1 : 0);
  const float maskv = (ri != rj) ? -100.0f : 0.0f;

  for (int h = 0; h < 8; ++h) {
    const BF16* qp = &sm[qi * 1544 + h * 64];
    const BF16* kp = &sm[kj * 1544 + 512 + h * 64];
    float acc = 0.0f;
#pragma unroll
    for (int d0 = 0; d0 < 8; ++d0) {
      bf16x8 qv = *(const bf16x8*)(qp + d0 * 8);
      bf16x8 kv = *(const bf16x8*)(kp + d0 * 8);
#pragma unroll
      for (int t = 0; t < 8; ++t) acc += (float)qv[t] * (float)kv[t];
    }
    float sc = acc * 0.125f + maskv;
    float mx = sc;
    mx = fmaxf(mx, __shfl_xor(mx, 1, 8));
    mx = fmaxf(mx, __shfl_xor(mx, 2, 8));
    mx = fmaxf(mx, __shfl_xor(mx, 4, 8));
    float e = __expf(sc - mx);
    float den = e;
    den += __shfl_xor(den, 1, 8);
    den += __shfl_xor(den, 2, 8);
    den += __shfl_xor(den, 4, 8);
    const float P = e / den;

    float o8[8];
#pragma unroll
    for (int t = 0; t < 8; ++t) o8[t] = 0.0f;
#pragma unroll
    for (int j2 = 0; j2 < 8; ++j2) {
      float p2 = __shfl(P, j2, 8);
      bf16x8 vv = *(const bf16x8*)(&sm[j2 * 1544 + 1024 + h * 64 + kj * 8]);
#pragma unroll
      for (int t = 0; t < 8; ++t) o8[t] += p2 * (float)vv[t];
    }
    BF16 ob[8];
#pragma unroll
    for (int t = 0; t < 8; ++t) ob[t] = __float2bfloat16(o8[t]);
    *(uint4*)(&out[((size_t)w * 8 + qi) * 512 + h * 64 + kj * 8]) = *(const uint4*)ob;
  }
}

// ---------------- launch ----------------
extern "C" void kernel_launch(void* const* d_in, const int* in_sizes, int n_in,
                              void* d_out, int out_size, void* d_ws, size_t ws_size,
                              hipStream_t stream) {
  (void)in_sizes; (void)n_in; (void)out_size; (void)ws_size;
  const float* x     = (const float*)d_in[0];
  const float* n1w   = (const float*)d_in[1];
  const float* n1b   = (const float*)d_in[2];
  const float* qkvw  = (const float*)d_in[3];
  const float* qkvb  = (const float*)d_in[4];
  const float* projw = (const float*)d_in[5];
  const float* projb = (const float*)d_in[6];
  const float* n2w   = (const float*)d_in[7];
  const float* n2b   = (const float*)d_in[8];
  const float* w1    = (const float*)d_in[9];
  const float* b1    = (const float*)d_in[10];
  const float* w2    = (const float*)d_in[11];
  const float* b2    = (const float*)d_in[12];
  float* out = (float*)d_out;
  char* ws = (char*)d_ws;

  BF16* wt_qkv  = (BF16*)(ws + OFF_WQKV);
  BF16* wt_proj = (BF16*)(ws + OFF_WPROJ);
  BF16* wt_w1   = (BF16*)(ws + OFF_W1);
  BF16* wt_w2   = (BF16*)(ws + OFF_W2);
  BF16* hbuf    = (BF16*)(ws + OFF_H);
  BF16* qkvbuf  = (BF16*)(ws + OFF_QKV);
  BF16* attnbuf = (BF16*)(ws + OFF_ATTN);
  BF16* mbuf    = (BF16*)(ws + OFF_M);

  wprep_all<<<768, 256, 0, stream>>>(qkvw, projw, w1, w2,
                                     wt_qkv, wt_proj, wt_w1, wt_w2);

  ln_kernel<<<16384, 256, 0, stream>>>(x, n1w, n1b, hbuf);
  gemm256<1, 0, 512><<<dim3(6, 256), 512, 0, stream>>>(hbuf, wt_qkv, qkvb, nullptr, nullptr, qkvbuf, 1536);
  attn_kernel<<<8192, 64, 0, stream>>>(qkvbuf, attnbuf);
  gemm256<0, 2, 512><<<dim3(2, 256), 512, 0, stream>>>(attnbuf, wt_proj, projb, x, out, nullptr, 512);
  ln_kernel<<<16384, 256, 0, stream>>>(out, n2w, n2b, hbuf);
  gemm256<0, 1, 512><<<dim3(8, 256), 512, 0, stream>>>(hbuf, wt_w1, b1, nullptr, nullptr, mbuf, 2048);
  gemm256<0, 3, 2048><<<dim3(2, 256), 512, 0, stream>>>(mbuf, wt_w2, b2, nullptr, out, nullptr, 512);
}